// Round 1
// baseline (1421.731 us; speedup 1.0000x reference)
//
#include <hip/hip_runtime.h>
#include <math.h>

// ---------------------------------------------------------------------------
// UDTransNet fused forward, fp32 baseline.
// Sizes: B=4, N=576, E=256, C=4E=1024, H=8, dh=32, M=4N=2304.
// ---------------------------------------------------------------------------

namespace {
constexpr int Bq  = 4;
constexpr int Nn  = 576;
constexpr int Ee  = 256;
constexpr int Cc  = 1024;
constexpr int DHh = 32;
constexpr int Mm  = 2304;                    // 4*N
constexpr long BNC = (long)Bq * Nn * Cc;     // 2359296
constexpr long NCl = (long)Nn * Cc;          // 589824 (per-batch stride of (N,C))
constexpr long BNE = (long)Bq * Nn * Ee;     // 589824 (per-q stride of (B,N,E))
constexpr long CCl = (long)Cc * Cc;          // 1048576
constexpr float EPSV = 1e-3f;
} // namespace

// ---------------------------------------------------------------------------
// Generic 64x64 fp32 GEMM, 256 threads, 4x4 micro-tile, K-tile 32.
// TA=0: A[m*lda+k]; TA=1: A[k*lda+m].  TB=0: B[k*ldb+n]; TB=1: B[n*ldb+k].
// RM=1: remap store for KV_S layout: out[((n>>8)*576 + m)*256 + (n&255)].
// All M,N divisible by 64; K divisible by 32 (no bounds checks).
// ---------------------------------------------------------------------------
template <int TA, int TB, int RM>
__global__ __launch_bounds__(256) void gemm64(
    const float* __restrict__ A, const float* __restrict__ B,
    float* __restrict__ C, int M, int N, int K,
    int lda, int ldb, int ldc, long sA, long sB, long sC)
{
  __shared__ float As[32][68];
  __shared__ float Bs[32][68];
  const int bz = blockIdx.z;
  A += sA * bz; B += sB * bz; C += sC * bz;
  const int n0 = blockIdx.x * 64, m0 = blockIdx.y * 64;
  const int t = threadIdx.x;
  const int tm = (t & 15) * 4, tn = (t >> 4) * 4;
  float acc[4][4] = {};

  for (int kt = 0; kt < K; kt += 32) {
    if (TA == 0) {
      #pragma unroll
      for (int it = 0; it < 2; ++it) {
        const int f = t + it * 256;            // 512 float4 = 64 rows x 8
        const int i = f >> 3, j4 = f & 7;
        const float4 v = *(const float4*)(A + (long)(m0 + i) * lda + kt + j4 * 4);
        As[j4 * 4 + 0][i] = v.x; As[j4 * 4 + 1][i] = v.y;
        As[j4 * 4 + 2][i] = v.z; As[j4 * 4 + 3][i] = v.w;
      }
    } else {
      #pragma unroll
      for (int it = 0; it < 2; ++it) {
        const int f = t + it * 256;            // 32 rows x 16
        const int j = f >> 4, i4 = f & 15;
        *(float4*)&As[j][i4 * 4] = *(const float4*)(A + (long)(kt + j) * lda + m0 + i4 * 4);
      }
    }
    if (TB == 0) {
      #pragma unroll
      for (int it = 0; it < 2; ++it) {
        const int f = t + it * 256;
        const int j = f >> 4, i4 = f & 15;
        *(float4*)&Bs[j][i4 * 4] = *(const float4*)(B + (long)(kt + j) * ldb + n0 + i4 * 4);
      }
    } else {
      #pragma unroll
      for (int it = 0; it < 2; ++it) {
        const int f = t + it * 256;
        const int i = f >> 3, j4 = f & 7;
        const float4 v = *(const float4*)(B + (long)(n0 + i) * ldb + kt + j4 * 4);
        Bs[j4 * 4 + 0][i] = v.x; Bs[j4 * 4 + 1][i] = v.y;
        Bs[j4 * 4 + 2][i] = v.z; Bs[j4 * 4 + 3][i] = v.w;
      }
    }
    __syncthreads();
    #pragma unroll
    for (int kk = 0; kk < 32; ++kk) {
      const float4 a4 = *(const float4*)&As[kk][tm];
      const float4 b4 = *(const float4*)&Bs[kk][tn];
      const float av[4] = {a4.x, a4.y, a4.z, a4.w};
      const float bv[4] = {b4.x, b4.y, b4.z, b4.w};
      #pragma unroll
      for (int i = 0; i < 4; ++i)
        #pragma unroll
        for (int j = 0; j < 4; ++j)
          acc[i][j] = fmaf(av[i], bv[j], acc[i][j]);
    }
    __syncthreads();
  }

  const int n = n0 + tn;
  #pragma unroll
  for (int i = 0; i < 4; ++i) {
    const int m = m0 + tm + i;
    const float4 o = make_float4(acc[i][0], acc[i][1], acc[i][2], acc[i][3]);
    if (RM) {
      const long dst = ((long)(n >> 8) * Nn + m) * Ee + (n & 255);
      *(float4*)&C[dst] = o;
    } else {
      *(float4*)&C[(long)m * ldc + n] = o;
    }
  }
}

// ---------------------------------------------------------------------------
// Stage-1 stats: sum & sumsq of attn_c per batch (atomics over 16 segs/batch).
// ---------------------------------------------------------------------------
__global__ void zero_sums(float* __restrict__ p)
{
  if (threadIdx.x < 8) p[threadIdx.x] = 0.f;
}

__global__ __launch_bounds__(256) void reduce_c_partial(
    const float* __restrict__ AC, float* __restrict__ sums)
{
  const int blk = blockIdx.x;          // 64 = 4 batches x 16 segments
  const int b = blk >> 4, seg = blk & 15;
  const float4* p = (const float4*)(AC + (long)b * CCl) + (long)seg * 16384;
  float s1 = 0.f, s2 = 0.f;
  for (int i = threadIdx.x; i < 16384; i += 256) {
    const float4 v = p[i];
    s1 += v.x + v.y + v.z + v.w;
    s2 += v.x * v.x + v.y * v.y + v.z * v.z + v.w * v.w;
  }
  __shared__ float r1[256], r2[256];
  const int t = threadIdx.x;
  r1[t] = s1; r2[t] = s2; __syncthreads();
  for (int s = 128; s > 0; s >>= 1) {
    if (t < s) { r1[t] += r1[t + s]; r2[t] += r2[t + s]; }
    __syncthreads();
  }
  if (t == 0) { atomicAdd(&sums[b * 2], r1[0]); atomicAdd(&sums[b * 2 + 1], r2[0]); }
}

// ---------------------------------------------------------------------------
// sim_c = softmax(attn_c * (gamma1*rsqrt(var+eps)), axis=-1), in place.
// (inorm's additive terms are constant along the softmax axis and drop out.)
// One block per row (B*C = 4096 rows of 1024).
// ---------------------------------------------------------------------------
__global__ __launch_bounds__(256) void softmax_c(
    float* __restrict__ AC, const float* __restrict__ sums, const float* __restrict__ g1)
{
  __shared__ float red[256];
  const long r = blockIdx.x;
  const int b = (int)(r >> 10);
  float* p = AC + r * Cc;
  const float invn = 1.f / (float)CCl;
  const float mean = sums[b * 2] * invn;
  const float var  = sums[b * 2 + 1] * invn - mean * mean;
  const float scb  = g1[0] * rsqrtf(var + EPSV);
  const int t = threadIdx.x;
  float4 v = ((const float4*)p)[t];
  v.x *= scb; v.y *= scb; v.z *= scb; v.w *= scb;
  float mx = fmaxf(fmaxf(v.x, v.y), fmaxf(v.z, v.w));
  red[t] = mx; __syncthreads();
  for (int s = 128; s > 0; s >>= 1) { if (t < s) red[t] = fmaxf(red[t], red[t + s]); __syncthreads(); }
  mx = red[0]; __syncthreads();
  v.x = __expf(v.x - mx); v.y = __expf(v.y - mx);
  v.z = __expf(v.z - mx); v.w = __expf(v.w - mx);
  red[t] = v.x + v.y + v.z + v.w; __syncthreads();
  for (int s = 128; s > 0; s >>= 1) { if (t < s) red[t] += red[t + s]; __syncthreads(); }
  const float inv = 1.f / red[0];
  v.x *= inv; v.y *= inv; v.z *= inv; v.w *= inv;
  ((float4*)p)[t] = v;
}

// ---------------------------------------------------------------------------
// 32x32 Gram matrix + column sums over a (ntiles*192) x 32 slab (rows strided
// by Ee). Used for the analytic mean/var of the stage-2 attention logits:
//   E[x^2] = sum_{d,e} Gq[d,e]*Gk[d,e]/(N*M),  mu = sum_d qbar_d*kbar_d/(N*M).
// ---------------------------------------------------------------------------
__device__ __forceinline__ void gram_accum(
    const float* __restrict__ slab, int ntiles,
    float* __restrict__ gout, float* __restrict__ msum)
{
  __shared__ float Ks[192][36];
  const int t = threadIdx.x;
  const int d = t >> 3, e0 = (t & 7) * 4;
  float g0 = 0.f, g1 = 0.f, g2 = 0.f, g3 = 0.f, cm = 0.f;
  for (int tile = 0; tile < ntiles; ++tile) {
    __syncthreads();
    #pragma unroll
    for (int it = 0; it < 6; ++it) {
      const int f = t + it * 256;              // 1536 float4 = 192 x 8
      const int row = f >> 3, j4 = f & 7;
      *(float4*)&Ks[row][j4 * 4] = *(const float4*)(slab + (long)(tile * 192 + row) * Ee + j4 * 4);
    }
    __syncthreads();
    #pragma unroll 4
    for (int m = 0; m < 192; ++m) {
      const float qd = Ks[m][d];
      const float4 qe = *(const float4*)&Ks[m][e0];
      g0 = fmaf(qd, qe.x, g0); g1 = fmaf(qd, qe.y, g1);
      g2 = fmaf(qd, qe.z, g2); g3 = fmaf(qd, qe.w, g3);
    }
    if (t < 32) {
      #pragma unroll 4
      for (int m = 0; m < 192; ++m) cm += Ks[m][t];
    }
  }
  float* gp = gout + d * 32 + e0;
  gp[0] = g0; gp[1] = g1; gp[2] = g2; gp[3] = g3;
  if (t < 32) msum[t] = cm;
}

__global__ __launch_bounds__(256) void gram_k_kernel(
    const float* __restrict__ Kb, float* __restrict__ Gk, float* __restrict__ km)
{
  const int blk = blockIdx.x;                  // b*8+h, 32 blocks
  gram_accum(Kb + ((long)(blk >> 3) * Mm) * Ee + (blk & 7) * DHh,
             12, Gk + (long)blk * 1024, km + blk * 32);
}

__global__ __launch_bounds__(256) void gram_q_kernel(
    const float* __restrict__ Qb, float* __restrict__ Gq, float* __restrict__ qm)
{
  const int blk = blockIdx.x;                  // q*32 + b*8 + h, 128 blocks
  const int qq = blk >> 5, b = (blk >> 3) & 3, h = blk & 7;
  gram_accum(Qb + (long)qq * BNE + ((long)b * Nn) * Ee + h * DHh,
             3, Gq + (long)blk * 1024, qm + blk * 32);
}

__global__ __launch_bounds__(128) void finalize_scale2(
    const float* __restrict__ Gq, const float* __restrict__ Gk,
    const float* __restrict__ qm, const float* __restrict__ km,
    const float* __restrict__ g2, float* __restrict__ sc2)
{
  const int i = threadIdx.x;                   // 0..127 = (q,b,h)
  const int kb = i & 31;                       // (b,h)
  const float* a  = Gq + (long)i * 1024;
  const float* bb = Gk + (long)kb * 1024;
  float s = 0.f;
  for (int j = 0; j < 1024; ++j) s += a[j] * bb[j];
  float mu = 0.f;
  const float* qa = qm + i * 32;
  const float* ka = km + kb * 32;
  for (int j = 0; j < 32; ++j) mu += qa[j] * ka[j];
  const float inv = 1.f / ((float)Nn * (float)Mm);
  const float ex2 = s * inv;
  const float m1  = mu * inv;
  sc2[i] = g2[i & 7] * rsqrtf(ex2 - m1 * m1 + EPSV);
}

// ---------------------------------------------------------------------------
// Flash attention for stage 2.  Grid (ntile=9, b*8+h=32, q=4), 256 threads.
// 64 Q-rows per block; K/V tiles of 128 in LDS; online softmax; the K tile
// and P tile share one LDS region (K dead once S is computed).
// Logit scale = gamma2[h]*rsqrt(var+eps) (inorm additive part drops out).
// ---------------------------------------------------------------------------
__global__ __launch_bounds__(256) void flash_attn(
    const float* __restrict__ Qb, const float* __restrict__ Kb,
    const float* __restrict__ Vb, const float* __restrict__ sc2,
    float* __restrict__ ctx)
{
  __shared__ float Qs[64][32];                 // swizzled slots
  __shared__ float Vt[32][132];                // V transposed: Vt[d][c]
  __shared__ float KP[8448];                   // union: K[128][32] / P[64][132]
  const int nt = blockIdx.x;
  const int bh = blockIdx.y;
  const int q  = blockIdx.z;
  const int b = bh >> 3, h = bh & 7;
  const int t = threadIdx.x;
  const int tx = t & 15, ty = t >> 4;
  const float sc = sc2[(q << 5) + bh];

  const float* Qp = Qb + (long)q * BNE + ((long)(b * Nn + nt * 64)) * Ee + h * DHh;
  #pragma unroll
  for (int it = 0; it < 2; ++it) {
    const int f = t + it * 256;
    const int row = f >> 3, j4 = f & 7;
    const int slot = (j4 ^ (row >> 3)) & 7;
    *(float4*)&Qs[row][slot * 4] = *(const float4*)(Qp + (long)row * Ee + j4 * 4);
  }

  float m_run[4], l_run[4], acc0[4], acc1[4];
  #pragma unroll
  for (int i = 0; i < 4; ++i) { m_run[i] = -1e30f; l_run[i] = 0.f; acc0[i] = 0.f; acc1[i] = 0.f; }

  const float* Kp = Kb + ((long)b * Mm) * Ee + h * DHh;
  const float* Vp = Vb + ((long)b * Mm) * Ee + h * DHh;

  for (int mt = 0; mt < 18; ++mt) {
    __syncthreads();                           // prev PV reads done
    #pragma unroll
    for (int it = 0; it < 4; ++it) {
      const int f = t + it * 256;              // 1024 float4 = 128 x 8
      const int row = f >> 3, j4 = f & 7;
      const int slot = (j4 ^ (row >> 3)) & 7;
      *(float4*)&KP[row * 32 + slot * 4] = *(const float4*)(Kp + (long)(mt * 128 + row) * Ee + j4 * 4);
    }
    #pragma unroll
    for (int it = 0; it < 4; ++it) {
      const int f = t + it * 256;
      const int row = f >> 3, j4 = f & 7;
      const float4 v = *(const float4*)(Vp + (long)(mt * 128 + row) * Ee + j4 * 4);
      Vt[j4 * 4 + 0][row] = v.x; Vt[j4 * 4 + 1][row] = v.y;
      Vt[j4 * 4 + 2][row] = v.z; Vt[j4 * 4 + 3][row] = v.w;
    }
    __syncthreads();                           // tiles visible

    // S = (Q K^T): thread owns rows ty*4..+3, cols tx*8..+7
    float s[4][8];
    #pragma unroll
    for (int i = 0; i < 4; ++i)
      #pragma unroll
      for (int j = 0; j < 8; ++j) s[i][j] = 0.f;

    #pragma unroll
    for (int kk4 = 0; kk4 < 8; ++kk4) {
      float4 qv[4];
      #pragma unroll
      for (int ri = 0; ri < 4; ++ri) {
        const int row = ty * 4 + ri;
        qv[ri] = *(const float4*)&Qs[row][((kk4 ^ (row >> 3)) & 7) * 4];
      }
      #pragma unroll
      for (int cj = 0; cj < 8; ++cj) {
        const int row = tx * 8 + cj;
        const float4 kv = *(const float4*)&KP[row * 32 + ((kk4 ^ (row >> 3)) & 7) * 4];
        #pragma unroll
        for (int ri = 0; ri < 4; ++ri) {
          s[ri][cj] = fmaf(qv[ri].x, kv.x, s[ri][cj]);
          s[ri][cj] = fmaf(qv[ri].y, kv.y, s[ri][cj]);
          s[ri][cj] = fmaf(qv[ri].z, kv.z, s[ri][cj]);
          s[ri][cj] = fmaf(qv[ri].w, kv.w, s[ri][cj]);
        }
      }
    }

    // online softmax (state replicated across the 16 tx lanes of a row group)
    #pragma unroll
    for (int ri = 0; ri < 4; ++ri) {
      float mloc = -1e30f;
      #pragma unroll
      for (int cj = 0; cj < 8; ++cj) { s[ri][cj] *= sc; mloc = fmaxf(mloc, s[ri][cj]); }
      mloc = fmaxf(mloc, __shfl_xor(mloc, 1));
      mloc = fmaxf(mloc, __shfl_xor(mloc, 2));
      mloc = fmaxf(mloc, __shfl_xor(mloc, 4));
      mloc = fmaxf(mloc, __shfl_xor(mloc, 8));
      const float mnew = fmaxf(m_run[ri], mloc);
      const float corr = __expf(m_run[ri] - mnew);
      float rs = 0.f;
      #pragma unroll
      for (int cj = 0; cj < 8; ++cj) {
        const float p = __expf(s[ri][cj] - mnew);
        s[ri][cj] = p; rs += p;
      }
      rs += __shfl_xor(rs, 1);
      rs += __shfl_xor(rs, 2);
      rs += __shfl_xor(rs, 4);
      rs += __shfl_xor(rs, 8);
      l_run[ri] = l_run[ri] * corr + rs;
      m_run[ri] = mnew;
      acc0[ri] *= corr; acc1[ri] *= corr;
    }
    __syncthreads();                           // all K reads done -> reuse as P

    #pragma unroll
    for (int ri = 0; ri < 4; ++ri) {
      const int row = ty * 4 + ri;
      *(float4*)&KP[row * 132 + tx * 8]     = make_float4(s[ri][0], s[ri][1], s[ri][2], s[ri][3]);
      *(float4*)&KP[row * 132 + tx * 8 + 4] = make_float4(s[ri][4], s[ri][5], s[ri][6], s[ri][7]);
    }
    __syncthreads();                           // P visible

    // PV: thread owns rows ty*4..+3, dims tx*2, tx*2+1
    #pragma unroll 8
    for (int kk4 = 0; kk4 < 32; ++kk4) {
      const float4 v0 = *(const float4*)&Vt[tx * 2 + 0][kk4 * 4];
      const float4 v1 = *(const float4*)&Vt[tx * 2 + 1][kk4 * 4];
      #pragma unroll
      for (int ri = 0; ri < 4; ++ri) {
        const float4 p4 = *(const float4*)&KP[(ty * 4 + ri) * 132 + kk4 * 4];
        acc0[ri] = fmaf(p4.x, v0.x, acc0[ri]);
        acc0[ri] = fmaf(p4.y, v0.y, acc0[ri]);
        acc0[ri] = fmaf(p4.z, v0.z, acc0[ri]);
        acc0[ri] = fmaf(p4.w, v0.w, acc0[ri]);
        acc1[ri] = fmaf(p4.x, v1.x, acc1[ri]);
        acc1[ri] = fmaf(p4.y, v1.y, acc1[ri]);
        acc1[ri] = fmaf(p4.z, v1.z, acc1[ri]);
        acc1[ri] = fmaf(p4.w, v1.w, acc1[ri]);
      }
    }
  }

  float* Op = ctx + (long)q * BNE + ((long)(b * Nn + nt * 64)) * Ee + h * DHh;
  #pragma unroll
  for (int ri = 0; ri < 4; ++ri) {
    const float inv = 1.f / l_run[ri];
    Op[(long)(ty * 4 + ri) * Ee + tx * 2 + 0] = acc0[ri] * inv;
    Op[(long)(ty * 4 + ri) * Ee + tx * 2 + 1] = acc1[ri] * inv;
  }
}

// ---------------------------------------------------------------------------
// Launcher.  Workspace layout (floats), ~46 MB total with aliasing:
//   QC [2359296] -> later KVS -> later ctx
//   KC [2359296] -> later Kbuf
//   VC [2359296] -> later Vbuf
//   AC [4194304] (attn_c / sim_c) -> later Qbuf (needs 2359296)
//   stats: sums[8] Gk[32768] km[1024] Gq[131072] qm[4096] sc2[128]
// ---------------------------------------------------------------------------
extern "C" void kernel_launch(void* const* d_in, const int* in_sizes, int n_in,
                              void* d_out, int out_size, void* d_ws, size_t ws_size,
                              hipStream_t stream)
{
  (void)in_sizes; (void)n_in; (void)out_size; (void)ws_size;
  const float* emb[4] = {(const float*)d_in[0], (const float*)d_in[1],
                         (const float*)d_in[2], (const float*)d_in[3]};
  const float* embC = (const float*)d_in[4];
  const float* WqC  = (const float*)d_in[5];
  const float* WkC  = (const float*)d_in[6];
  const float* WvC  = (const float*)d_in[7];
  const float* Wq[4] = {(const float*)d_in[8], (const float*)d_in[9],
                        (const float*)d_in[10], (const float*)d_in[11]};
  const float* Wk = (const float*)d_in[12];
  const float* Wv = (const float*)d_in[13];
  const float* Wo[4] = {(const float*)d_in[14], (const float*)d_in[15],
                        (const float*)d_in[16], (const float*)d_in[17]};
  const float* gamma1 = (const float*)d_in[18];
  const float* gamma2 = (const float*)d_in[20];
  float* out = (float*)d_out;

  float* QC  = (float*)d_ws;
  float* KC  = QC + BNC;
  float* VC  = KC + BNC;
  float* ACb = VC + BNC;
  float* stats = ACb + (long)Bq * CCl;
  float* sums = stats;              // 8
  float* Gk   = stats + 8;          // 32*1024
  float* km   = Gk + 32 * 1024;     // 32*32
  float* Gq   = km + 1024;          // 128*1024
  float* qm   = Gq + 128 * 1024;    // 128*32
  float* sc2  = qm + 4096;          // 128
  float* KVS  = QC;                 // alias: QC dead after attn_c
  float* Kbuf = KC;                 // alias: KC dead after attn_c
  float* Vbuf = VC;                 // alias: VC dead after T_hat
  float* Qbuf = ACb;                // alias: sim_c dead after T_hat
  float* ctx  = QC;                 // alias: KVS dead after K/V projections

  const dim3 th(256);

  // Stage A: QC/KC/VC = emb_C @ W*_C   (M=2304, N=1024, K=1024)
  gemm64<0,0,0><<<dim3(16,36,1), th, 0, stream>>>(embC, WqC, QC, 2304,1024,1024, 1024,1024,1024, 0,0,0);
  gemm64<0,0,0><<<dim3(16,36,1), th, 0, stream>>>(embC, WkC, KC, 2304,1024,1024, 1024,1024,1024, 0,0,0);
  gemm64<0,0,0><<<dim3(16,36,1), th, 0, stream>>>(embC, WvC, VC, 2304,1024,1024, 1024,1024,1024, 0,0,0);

  // attn_c[b] = QC[b]^T @ KC[b]   (M=N=1024, K=576, batched over b)
  gemm64<1,0,0><<<dim3(16,16,4), th, 0, stream>>>(QC, KC, ACb, 1024,1024,576, 1024,1024,1024, NCl,NCl,CCl);

  // per-batch mean/var -> softmax scale; softmax in place
  zero_sums<<<1, 64, 0, stream>>>(sums);
  reduce_c_partial<<<64, th, 0, stream>>>(ACb, sums);
  softmax_c<<<4096, th, 0, stream>>>(ACb, sums, gamma1);

  // T_hat[b] = VC[b] @ sim_c[b]^T, stored directly in KV_S layout
  gemm64<0,1,1><<<dim3(16,9,4), th, 0, stream>>>(VC, ACb, KVS, 576,1024,1024, 1024,1024,256, NCl,CCl,NCl);

  // K/V projections: (B*4N=9216, 256) @ (256,256)
  gemm64<0,0,0><<<dim3(4,144,1), th, 0, stream>>>(KVS, Wk, Kbuf, 9216,256,256, 256,256,256, 0,0,0);
  gemm64<0,0,0><<<dim3(4,144,1), th, 0, stream>>>(KVS, Wv, Vbuf, 9216,256,256, 256,256,256, 0,0,0);

  // Q projections: 4 x (2304,256)@(256,256)
  for (int qq = 0; qq < 4; ++qq)
    gemm64<0,0,0><<<dim3(4,36,1), th, 0, stream>>>(emb[qq], Wq[qq], Qbuf + (long)qq * BNE,
                                                   2304,256,256, 256,256,256, 0,0,0);

  // analytic inorm scales for stage-2 attention
  gram_k_kernel<<<32, th, 0, stream>>>(Kbuf, Gk, km);
  gram_q_kernel<<<128, th, 0, stream>>>(Qbuf, Gq, qm);
  finalize_scale2<<<1, 128, 0, stream>>>(Gq, Gk, qm, km, gamma2, sc2);

  // flash attention -> ctx (4,B,N,E)
  flash_attn<<<dim3(9,32,4), th, 0, stream>>>(Qbuf, Kbuf, Vbuf, sc2, ctx);

  // output projections -> d_out (4 outputs concatenated)
  for (int qq = 0; qq < 4; ++qq)
    gemm64<0,0,0><<<dim3(4,36,1), th, 0, stream>>>(ctx + (long)qq * BNE, Wo[qq], out + (long)qq * BNE,
                                                   2304,256,256, 256,256,256, 0,0,0);
}

// Round 2
// 855.158 us; speedup vs baseline: 1.6625x; 1.6625x over previous
//
#include <hip/hip_runtime.h>
#include <math.h>

// ---------------------------------------------------------------------------
// UDTransNet fused forward. fp16 MFMA for all GEMM-shaped work, fp32 accum.
// Sizes: B=4, N=576, E=256, C=4E=1024, H=8, dh=32, M=4N=2304.
// ---------------------------------------------------------------------------

namespace {
constexpr int Bq  = 4;
constexpr int Nn  = 576;
constexpr int Ee  = 256;
constexpr int Cc  = 1024;
constexpr int Mm  = 2304;                    // 4*N
constexpr long BNC = (long)Bq * Nn * Cc;     // 2359296
constexpr long NCl = (long)Nn * Cc;          // 589824
constexpr long BNE = (long)Bq * Nn * Ee;     // 589824
constexpr long CCl = (long)Cc * Cc;          // 1048576
constexpr float EPSV = 1e-3f;
constexpr float LOG2E = 1.4426950408889634f;
} // namespace

typedef _Float16 h8 __attribute__((ext_vector_type(8)));
typedef _Float16 h4 __attribute__((ext_vector_type(4)));
typedef float    f4 __attribute__((ext_vector_type(4)));

// ---------------------------------------------------------------------------
// MFMA GEMM: BM=64, BN=128, BK=32, 256 threads (4 waves, 2x2 wave grid).
// D[m][n] = sum_k A[m][k]*B[k][n], fp32 in/out, fp16 compute, fp32 accum.
// TA=0: A global [m][k] (lda=k-stride). TA=1: A global [k][m].
// TB=0: B global [k][n].               TB=1: B global [n][k].
// RM=1: KV_S remap store: C[((n>>8)*576 + m)*256 + (n&255)].
// M%64==0, N%128==0, K%32==0.
// Fragment model for v_mfma_f32_16x16x32_f16 (k-permutation invariant):
//   a: lane l holds A[m0+(l&15)][(l>>4)*8+j]; b mirrored; d: row=(l>>4)*4+r,
//   col=(l&15)  [C/D layout HW-verified].
// ---------------------------------------------------------------------------
template <int TA, int TB, int RM>
__device__ __forceinline__ void mgemm_body(
    const float* __restrict__ A, const float* __restrict__ B,
    float* __restrict__ C, int K, int lda, int ldb, int ldc)
{
  __shared__ _Float16 As[64][40];    // [m][k], pad 8
  __shared__ _Float16 Bs[128][40];   // [n][k], pad 8
  const int n0 = blockIdx.x * 128, m0 = blockIdx.y * 64;
  const int t = threadIdx.x;
  const int w = t >> 6, l = t & 63, lg = l >> 4, lr = l & 15;
  const int wm = (w & 1) * 32, wn = (w >> 1) * 64;

  f4 acc[2][4];
  #pragma unroll
  for (int i = 0; i < 2; ++i)
    #pragma unroll
    for (int j = 0; j < 4; ++j) acc[i][j] = (f4){0.f, 0.f, 0.f, 0.f};

  for (int kt = 0; kt < K; kt += 32) {
    if (TA == 0) {
      #pragma unroll
      for (int it = 0; it < 2; ++it) {
        const int f = t + it * 256, row = f >> 3, j4 = f & 7;
        const float4 v = *(const float4*)(A + (long)(m0 + row) * lda + kt + j4 * 4);
        h4 hv = {(_Float16)v.x, (_Float16)v.y, (_Float16)v.z, (_Float16)v.w};
        *(h4*)&As[row][j4 * 4] = hv;
      }
    } else {
      #pragma unroll
      for (int it = 0; it < 2; ++it) {
        const int f = t + it * 256, k = f >> 4, m4 = (f & 15) * 4;
        const float4 v = *(const float4*)(A + (long)(kt + k) * lda + m0 + m4);
        As[m4 + 0][k] = (_Float16)v.x; As[m4 + 1][k] = (_Float16)v.y;
        As[m4 + 2][k] = (_Float16)v.z; As[m4 + 3][k] = (_Float16)v.w;
      }
    }
    if (TB == 0) {
      #pragma unroll
      for (int it = 0; it < 4; ++it) {
        const int f = t + it * 256, k = f >> 5, n4 = (f & 31) * 4;
        const float4 v = *(const float4*)(B + (long)(kt + k) * ldb + n0 + n4);
        Bs[n4 + 0][k] = (_Float16)v.x; Bs[n4 + 1][k] = (_Float16)v.y;
        Bs[n4 + 2][k] = (_Float16)v.z; Bs[n4 + 3][k] = (_Float16)v.w;
      }
    } else {
      #pragma unroll
      for (int it = 0; it < 4; ++it) {
        const int f = t + it * 256, row = f >> 3, j4 = f & 7;
        const float4 v = *(const float4*)(B + (long)(n0 + row) * ldb + kt + j4 * 4);
        h4 hv = {(_Float16)v.x, (_Float16)v.y, (_Float16)v.z, (_Float16)v.w};
        *(h4*)&Bs[row][j4 * 4] = hv;
      }
    }
    __syncthreads();

    h8 af[2];
    #pragma unroll
    for (int mf = 0; mf < 2; ++mf) af[mf] = *(const h8*)&As[wm + mf * 16 + lr][lg * 8];
    #pragma unroll
    for (int nf = 0; nf < 4; ++nf) {
      const h8 bf = *(const h8*)&Bs[wn + nf * 16 + lr][lg * 8];
      acc[0][nf] = __builtin_amdgcn_mfma_f32_16x16x32_f16(af[0], bf, acc[0][nf], 0, 0, 0);
      acc[1][nf] = __builtin_amdgcn_mfma_f32_16x16x32_f16(af[1], bf, acc[1][nf], 0, 0, 0);
    }
    __syncthreads();
  }

  #pragma unroll
  for (int mf = 0; mf < 2; ++mf)
    #pragma unroll
    for (int nf = 0; nf < 4; ++nf)
      #pragma unroll
      for (int r = 0; r < 4; ++r) {
        const int m = m0 + wm + mf * 16 + lg * 4 + r;
        const int n = n0 + wn + nf * 16 + lr;
        const float v = acc[mf][nf][r];
        if (RM) {
          const long dst = ((long)(n >> 8) * Nn + m) * Ee + (n & 255);
          C[dst] = v;
        } else {
          C[(long)m * ldc + n] = v;
        }
      }
}

template <int TA, int TB, int RM>
__global__ __launch_bounds__(256) void mgemm(
    const float* __restrict__ A, const float* __restrict__ B, float* __restrict__ C,
    int K, int lda, int ldb, int ldc, long sA, long sB, long sC)
{
  const int bz = blockIdx.z;
  mgemm_body<TA, TB, RM>(A + sA * bz, B + sB * bz, C + sC * bz, K, lda, ldb, ldc);
}

struct P4 { const float* A[4]; const float* W[4]; float* O[4]; };

__global__ __launch_bounds__(256) void mgemm_b4(P4 p, int K, int lda, int ldb, int ldc)
{
  const int bz = blockIdx.z;
  mgemm_body<0, 0, 0>(p.A[bz], p.W[bz], p.O[bz], K, lda, ldb, ldc);
}

// ---------------------------------------------------------------------------
// Stage-1 stats: sum & sumsq of attn_c per batch.
// ---------------------------------------------------------------------------
__global__ void zero_sums(float* __restrict__ p)
{
  if (threadIdx.x < 8) p[threadIdx.x] = 0.f;
}

__global__ __launch_bounds__(256) void reduce_c_partial(
    const float* __restrict__ AC, float* __restrict__ sums)
{
  const int blk = blockIdx.x;          // 64 = 4 batches x 16 segments
  const int b = blk >> 4, seg = blk & 15;
  const float4* p = (const float4*)(AC + (long)b * CCl) + (long)seg * 16384;
  float s1 = 0.f, s2 = 0.f;
  for (int i = threadIdx.x; i < 16384; i += 256) {
    const float4 v = p[i];
    s1 += v.x + v.y + v.z + v.w;
    s2 += v.x * v.x + v.y * v.y + v.z * v.z + v.w * v.w;
  }
  __shared__ float r1[256], r2[256];
  const int t = threadIdx.x;
  r1[t] = s1; r2[t] = s2; __syncthreads();
  for (int s = 128; s > 0; s >>= 1) {
    if (t < s) { r1[t] += r1[t + s]; r2[t] += r2[t + s]; }
    __syncthreads();
  }
  if (t == 0) { atomicAdd(&sums[b * 2], r1[0]); atomicAdd(&sums[b * 2 + 1], r2[0]); }
}

// ---------------------------------------------------------------------------
// sim_c = softmax(attn_c * gamma1*rsqrt(var+eps), axis=-1), in place.
// ---------------------------------------------------------------------------
__global__ __launch_bounds__(256) void softmax_c(
    float* __restrict__ AC, const float* __restrict__ sums, const float* __restrict__ g1)
{
  __shared__ float red[256];
  const long r = blockIdx.x;
  const int b = (int)(r >> 10);
  float* p = AC + r * Cc;
  const float invn = 1.f / (float)CCl;
  const float mean = sums[b * 2] * invn;
  const float var  = sums[b * 2 + 1] * invn - mean * mean;
  const float scb  = g1[0] * rsqrtf(var + EPSV);
  const int t = threadIdx.x;
  float4 v = ((const float4*)p)[t];
  v.x *= scb; v.y *= scb; v.z *= scb; v.w *= scb;
  float mx = fmaxf(fmaxf(v.x, v.y), fmaxf(v.z, v.w));
  red[t] = mx; __syncthreads();
  for (int s = 128; s > 0; s >>= 1) { if (t < s) red[t] = fmaxf(red[t], red[t + s]); __syncthreads(); }
  mx = red[0]; __syncthreads();
  v.x = __expf(v.x - mx); v.y = __expf(v.y - mx);
  v.z = __expf(v.z - mx); v.w = __expf(v.w - mx);
  red[t] = v.x + v.y + v.z + v.w; __syncthreads();
  for (int s = 128; s > 0; s >>= 1) { if (t < s) red[t] += red[t + s]; __syncthreads(); }
  const float inv = 1.f / red[0];
  v.x *= inv; v.y *= inv; v.z *= inv; v.w *= inv;
  ((float4*)p)[t] = v;
}

// ---------------------------------------------------------------------------
// 32x32 Gram + column sums for analytic stage-2 inorm scale.
// ---------------------------------------------------------------------------
__device__ __forceinline__ void gram_accum(
    const float* __restrict__ slab, int ntiles,
    float* __restrict__ gout, float* __restrict__ msum)
{
  __shared__ float Ks[192][36];
  const int t = threadIdx.x;
  const int d = t >> 3, e0 = (t & 7) * 4;
  float g0 = 0.f, g1 = 0.f, g2 = 0.f, g3 = 0.f, cm = 0.f;
  for (int tile = 0; tile < ntiles; ++tile) {
    __syncthreads();
    #pragma unroll
    for (int it = 0; it < 6; ++it) {
      const int f = t + it * 256;
      const int row = f >> 3, j4 = f & 7;
      *(float4*)&Ks[row][j4 * 4] = *(const float4*)(slab + (long)(tile * 192 + row) * Ee + j4 * 4);
    }
    __syncthreads();
    #pragma unroll 4
    for (int m = 0; m < 192; ++m) {
      const float qd = Ks[m][d];
      const float4 qe = *(const float4*)&Ks[m][e0];
      g0 = fmaf(qd, qe.x, g0); g1 = fmaf(qd, qe.y, g1);
      g2 = fmaf(qd, qe.z, g2); g3 = fmaf(qd, qe.w, g3);
    }
    if (t < 32) {
      #pragma unroll 4
      for (int m = 0; m < 192; ++m) cm += Ks[m][t];
    }
  }
  float* gp = gout + d * 32 + e0;
  gp[0] = g0; gp[1] = g1; gp[2] = g2; gp[3] = g3;
  if (t < 32) msum[t] = cm;
}

__global__ __launch_bounds__(256) void gram_k_kernel(
    const float* __restrict__ Kb, float* __restrict__ Gk, float* __restrict__ km)
{
  const int blk = blockIdx.x;                  // b*8+h
  gram_accum(Kb + ((long)(blk >> 3) * Mm) * Ee + (blk & 7) * 32,
             12, Gk + (long)blk * 1024, km + blk * 32);
}

__global__ __launch_bounds__(256) void gram_q_kernel(
    const float* __restrict__ Qb, float* __restrict__ Gq, float* __restrict__ qm)
{
  const int blk = blockIdx.x;                  // q*32 + b*8 + h
  const int qq = blk >> 5, b = (blk >> 3) & 3, h = blk & 7;
  gram_accum(Qb + (long)qq * BNE + ((long)b * Nn) * Ee + h * 32,
             3, Gq + (long)blk * 1024, qm + blk * 32);
}

__global__ __launch_bounds__(128) void finalize_scale2(
    const float* __restrict__ Gq, const float* __restrict__ Gk,
    const float* __restrict__ qm, const float* __restrict__ km,
    const float* __restrict__ g2, float* __restrict__ sc2)
{
  const int i = threadIdx.x;                   // (q,b,h)
  const int kb = i & 31;
  const float* a  = Gq + (long)i * 1024;
  const float* bb = Gk + (long)kb * 1024;
  float s = 0.f;
  for (int j = 0; j < 1024; ++j) s += a[j] * bb[j];
  float mu = 0.f;
  const float* qa = qm + i * 32;
  const float* ka = km + kb * 32;
  for (int j = 0; j < 32; ++j) mu += qa[j] * ka[j];
  const float inv = 1.f / ((float)Nn * (float)Mm);
  const float ex2 = s * inv;
  const float m1  = mu * inv;
  // fold log2(e): flash uses exp2
  sc2[i] = g2[i & 7] * rsqrtf(ex2 - m1 * m1 + EPSV) * LOG2E;
}

// ---------------------------------------------------------------------------
// MFMA flash attention, stage 2. Grid (ntile=9, b*8+h=32, q=4), 256 thr.
// 64 Q-rows/block (16/wave), KV tiles of 128. Q/K/V fp16 in LDS, online
// softmax in exp2-domain (scale pre-multiplied by log2e), P via LDS.
// ---------------------------------------------------------------------------
__global__ __launch_bounds__(256) void flash2(
    const float* __restrict__ Qb, const float* __restrict__ Kb,
    const float* __restrict__ Vb, const float* __restrict__ sc2,
    float* __restrict__ ctx)
{
  __shared__ _Float16 Qs[64][40];     // [q][d]
  __shared__ _Float16 Ks[128][40];    // [kv][d]
  __shared__ _Float16 Vt[32][136];    // [d][kv]
  __shared__ _Float16 Ps[64][136];    // [q][kv]
  const int nt = blockIdx.x, bh = blockIdx.y, q = blockIdx.z;
  const int b = bh >> 3, h = bh & 7;
  const int t = threadIdx.x, w = t >> 6, l = t & 63, lg = l >> 4, lr = l & 15;
  const float sc = sc2[(q << 5) + bh];     // gamma2*rsqrt(var+eps)*log2e

  const float* Qp = Qb + (long)q * BNE + (long)(b * Nn + nt * 64) * Ee + h * 32;
  #pragma unroll
  for (int it = 0; it < 2; ++it) {
    const int f = t + it * 256, row = f >> 3, j4 = f & 7;
    const float4 v = *(const float4*)(Qp + (long)row * Ee + j4 * 4);
    h4 hv = {(_Float16)v.x, (_Float16)v.y, (_Float16)v.z, (_Float16)v.w};
    *(h4*)&Qs[row][j4 * 4] = hv;
  }
  __syncthreads();
  const h8 qf = *(const h8*)&Qs[w * 16 + lr][lg * 8];

  float m_run[4], l_run[4];
  f4 cacc[2];
  #pragma unroll
  for (int r = 0; r < 4; ++r) { m_run[r] = -1e30f; l_run[r] = 0.f; }
  cacc[0] = (f4){0.f, 0.f, 0.f, 0.f};
  cacc[1] = (f4){0.f, 0.f, 0.f, 0.f};

  const float* Kp = Kb + ((long)b * Mm) * Ee + h * 32;
  const float* Vp = Vb + ((long)b * Mm) * Ee + h * 32;

  for (int mt = 0; mt < 18; ++mt) {
    __syncthreads();                         // prev-iter K/V reads done
    #pragma unroll
    for (int it = 0; it < 4; ++it) {
      const int f = t + it * 256, row = f >> 3, j4 = f & 7;
      const float4 v = *(const float4*)(Kp + (long)(mt * 128 + row) * Ee + j4 * 4);
      h4 hv = {(_Float16)v.x, (_Float16)v.y, (_Float16)v.z, (_Float16)v.w};
      *(h4*)&Ks[row][j4 * 4] = hv;
    }
    #pragma unroll
    for (int it = 0; it < 4; ++it) {
      const int f = t + it * 256, row = f >> 3, j4 = f & 7;
      const float4 v = *(const float4*)(Vp + (long)(mt * 128 + row) * Ee + j4 * 4);
      Vt[j4 * 4 + 0][row] = (_Float16)v.x; Vt[j4 * 4 + 1][row] = (_Float16)v.y;
      Vt[j4 * 4 + 2][row] = (_Float16)v.z; Vt[j4 * 4 + 3][row] = (_Float16)v.w;
    }
    __syncthreads();                         // tiles visible

    // S = Q K^T : 8 kv-frags of 16, one MFMA each (full K=32)
    f4 s[8];
    #pragma unroll
    for (int nf = 0; nf < 8; ++nf) {
      const h8 kf = *(const h8*)&Ks[nf * 16 + lr][lg * 8];
      s[nf] = __builtin_amdgcn_mfma_f32_16x16x32_f16(qf, kf, (f4){0.f, 0.f, 0.f, 0.f}, 0, 0, 0);
    }

    // online softmax (rows (lg*4+r); cols lr + 16*nf)
    #pragma unroll
    for (int r = 0; r < 4; ++r) {
      float mx = -1e30f;
      #pragma unroll
      for (int nf = 0; nf < 8; ++nf) { s[nf][r] *= sc; mx = fmaxf(mx, s[nf][r]); }
      mx = fmaxf(mx, __shfl_xor(mx, 1));
      mx = fmaxf(mx, __shfl_xor(mx, 2));
      mx = fmaxf(mx, __shfl_xor(mx, 4));
      mx = fmaxf(mx, __shfl_xor(mx, 8));
      const float mnew = fmaxf(m_run[r], mx);
      const float corr = exp2f(m_run[r] - mnew);
      float rs = 0.f;
      #pragma unroll
      for (int nf = 0; nf < 8; ++nf) {
        const float p = exp2f(s[nf][r] - mnew);
        s[nf][r] = p; rs += p;
      }
      rs += __shfl_xor(rs, 1);
      rs += __shfl_xor(rs, 2);
      rs += __shfl_xor(rs, 4);
      rs += __shfl_xor(rs, 8);
      l_run[r] = l_run[r] * corr + rs;
      m_run[r] = mnew;
      cacc[0][r] *= corr; cacc[1][r] *= corr;
    }

    // P -> LDS (each wave writes/reads only its own 16 rows; no barrier)
    #pragma unroll
    for (int nf = 0; nf < 8; ++nf)
      #pragma unroll
      for (int r = 0; r < 4; ++r)
        Ps[w * 16 + lg * 4 + r][nf * 16 + lr] = (_Float16)s[nf][r];

    // ctx += P V : k-steps of 32 kv, 2 d-frags
    #pragma unroll
    for (int ks = 0; ks < 4; ++ks) {
      const h8 pf = *(const h8*)&Ps[w * 16 + lr][ks * 32 + lg * 8];
      #pragma unroll
      for (int df = 0; df < 2; ++df) {
        const h8 vf = *(const h8*)&Vt[df * 16 + lr][ks * 32 + lg * 8];
        cacc[df] = __builtin_amdgcn_mfma_f32_16x16x32_f16(pf, vf, cacc[df], 0, 0, 0);
      }
    }
  }

  float* Op = ctx + (long)q * BNE + (long)(b * Nn + nt * 64) * Ee + h * 32;
  #pragma unroll
  for (int r = 0; r < 4; ++r) {
    const float inv = 1.f / l_run[r];
    const long row = w * 16 + lg * 4 + r;
    Op[row * Ee + 0  + lr] = cacc[0][r] * inv;
    Op[row * Ee + 16 + lr] = cacc[1][r] * inv;
  }
}

// ---------------------------------------------------------------------------
// Launcher. Workspace (floats, ~46 MB with aliasing):
//   QC [BNC] -> KVS -> ctx ; KC [BNC] -> Kbuf ; VC [BNC] -> Vbuf ;
//   AC [4*CCl] -> Qbuf ; stats.
// ---------------------------------------------------------------------------
extern "C" void kernel_launch(void* const* d_in, const int* in_sizes, int n_in,
                              void* d_out, int out_size, void* d_ws, size_t ws_size,
                              hipStream_t stream)
{
  (void)in_sizes; (void)n_in; (void)out_size; (void)ws_size;
  const float* emb[4] = {(const float*)d_in[0], (const float*)d_in[1],
                         (const float*)d_in[2], (const float*)d_in[3]};
  const float* embC = (const float*)d_in[4];
  const float* WqC  = (const float*)d_in[5];
  const float* WkC  = (const float*)d_in[6];
  const float* WvC  = (const float*)d_in[7];
  const float* Wq[4] = {(const float*)d_in[8], (const float*)d_in[9],
                        (const float*)d_in[10], (const float*)d_in[11]};
  const float* Wk = (const float*)d_in[12];
  const float* Wv = (const float*)d_in[13];
  const float* Wo[4] = {(const float*)d_in[14], (const float*)d_in[15],
                        (const float*)d_in[16], (const float*)d_in[17]};
  const float* gamma1 = (const float*)d_in[18];
  const float* gamma2 = (const float*)d_in[20];
  float* out = (float*)d_out;

  float* QC  = (float*)d_ws;
  float* KC  = QC + BNC;
  float* VC  = KC + BNC;
  float* ACb = VC + BNC;
  float* stats = ACb + (long)Bq * CCl;
  float* sums = stats;              // 8
  float* Gk   = stats + 8;          // 32*1024
  float* km   = Gk + 32 * 1024;     // 32*32
  float* Gq   = km + 1024;          // 128*1024
  float* qm   = Gq + 128 * 1024;    // 128*32
  float* sc2  = qm + 4096;          // 128
  float* KVS  = QC;
  float* Kbuf = KC;
  float* Vbuf = VC;
  float* Qbuf = ACb;
  float* ctx  = QC;

  const dim3 th(256);

  // Stage A: QC/KC/VC = emb_C @ W*_C  (M=2304, N=1024, K=1024)
  mgemm<0,0,0><<<dim3(8,36,1), th, 0, stream>>>(embC, WqC, QC, 1024, 1024,1024,1024, 0,0,0);
  mgemm<0,0,0><<<dim3(8,36,1), th, 0, stream>>>(embC, WkC, KC, 1024, 1024,1024,1024, 0,0,0);
  mgemm<0,0,0><<<dim3(8,36,1), th, 0, stream>>>(embC, WvC, VC, 1024, 1024,1024,1024, 0,0,0);

  // attn_c[b] = QC[b]^T @ KC[b]  (M=N=1024, K=576)
  mgemm<1,0,0><<<dim3(8,16,4), th, 0, stream>>>(QC, KC, ACb, 576, 1024,1024,1024, NCl,NCl,CCl);

  zero_sums<<<1, 64, 0, stream>>>(sums);
  reduce_c_partial<<<64, th, 0, stream>>>(ACb, sums);
  softmax_c<<<4096, th, 0, stream>>>(ACb, sums, gamma1);

  // T_hat[b] = VC[b] @ sim_c[b]^T -> KV_S layout  (M=576, N=1024, K=1024)
  mgemm<0,1,1><<<dim3(8,9,4), th, 0, stream>>>(VC, ACb, KVS, 1024, 1024,1024,256, NCl,CCl,NCl);

  // K/V projections: (9216,256) @ (256,256)
  mgemm<0,0,0><<<dim3(2,144,1), th, 0, stream>>>(KVS, Wk, Kbuf, 256, 256,256,256, 0,0,0);
  mgemm<0,0,0><<<dim3(2,144,1), th, 0, stream>>>(KVS, Wv, Vbuf, 256, 256,256,256, 0,0,0);

  // Q projections: 4 x (2304,256)@(256,256), batched over z
  {
    P4 p;
    for (int i = 0; i < 4; ++i) { p.A[i] = emb[i]; p.W[i] = Wq[i]; p.O[i] = Qbuf + (long)i * BNE; }
    mgemm_b4<<<dim3(2,36,4), th, 0, stream>>>(p, 256, 256,256,256);
  }

  // analytic inorm scales for stage-2 attention
  gram_k_kernel<<<32, th, 0, stream>>>(Kbuf, Gk, km);
  gram_q_kernel<<<128, th, 0, stream>>>(Qbuf, Gq, qm);
  finalize_scale2<<<1, 128, 0, stream>>>(Gq, Gk, qm, km, gamma2, sc2);

  // flash attention -> ctx (4,B,N,E)
  flash2<<<dim3(9,32,4), th, 0, stream>>>(Qbuf, Kbuf, Vbuf, sc2, ctx);

  // output projections, batched over z
  {
    P4 p;
    for (int i = 0; i < 4; ++i) { p.A[i] = ctx + (long)i * BNE; p.W[i] = Wo[i]; p.O[i] = out + (long)i * BNE; }
    mgemm_b4<<<dim3(2,36,4), th, 0, stream>>>(p, 256, 256,256,256);
  }
}

// Round 3
// 502.245 us; speedup vs baseline: 2.8308x; 1.7027x over previous
//
#include <hip/hip_runtime.h>
#include <math.h>

// ---------------------------------------------------------------------------
// UDTransNet fused forward. All GEMM-shaped work on fp16 MFMA (fp32 accum),
// fp16 intermediates, analytic inorm scales, swapped-QK^T flash attention.
// Sizes: B=4, N=576, E=256, C=1024, H=8, dh=32, M=4N=2304.
// ---------------------------------------------------------------------------

namespace {
constexpr int Bq  = 4;
constexpr int Nn  = 576;
constexpr int Ee  = 256;
constexpr int Cc  = 1024;
constexpr int Mm  = 2304;
constexpr long BNE = (long)Bq * Nn * Ee;     // 589824
constexpr long CCl = (long)Cc * Cc;          // 1048576
constexpr float EPSV = 1e-3f;
constexpr float LOG2E = 1.4426950408889634f;
} // namespace

typedef _Float16 h16;
typedef _Float16 h8v __attribute__((ext_vector_type(8)));
typedef _Float16 h4v __attribute__((ext_vector_type(4)));
typedef float    f4v __attribute__((ext_vector_type(4)));

// ---------------------------------------------------------------------------
// One-shot fp32 -> fp16 conversion of all reused GEMM operands.
// Index space (halves): [0,2359296) embC | [..,5505024) Wc (QKV interleaved
// rows of 3072) | [..,5636096) Wkv | [..,5898240) Wq1-4 | [..,6160384) Wo1-4.
// ---------------------------------------------------------------------------
struct CvtP {
  const float* embC; const float* WqC; const float* WkC; const float* WvC;
  const float* Wk; const float* Wv;
  const float* Wq[4]; const float* Wo[4];
  h16* dEmbC; h16* dWc; h16* dWkv; h16* dWq; h16* dWo;
};

__global__ __launch_bounds__(256) void convert_all(CvtP p)
{
  const long i4 = ((long)blockIdx.x * 256 + threadIdx.x) * 4;
  if (i4 >= 6160384L) return;
  float4 v; h16* dst;
  if (i4 < 2359296L) {
    v = *(const float4*)(p.embC + i4); dst = p.dEmbC + i4;
  } else if (i4 < 5505024L) {
    const long d = i4 - 2359296L;
    const int k = (int)(d / 3072), c = (int)(d - (long)k * 3072);
    const float* W = c < 1024 ? p.WqC : (c < 2048 ? p.WkC : p.WvC);
    v = *(const float4*)(W + (long)k * 1024 + (c & 1023)); dst = p.dWc + d;
  } else if (i4 < 5636096L) {
    const long d = i4 - 5505024L;
    const int k = (int)(d >> 9), c = (int)(d & 511);
    const float* W = c < 256 ? p.Wk : p.Wv;
    v = *(const float4*)(W + (long)k * 256 + (c & 255)); dst = p.dWkv + d;
  } else if (i4 < 5898240L) {
    const long d = i4 - 5636096L;
    v = *(const float4*)(p.Wq[d >> 16] + (d & 65535)); dst = p.dWq + d;
  } else {
    const long d = i4 - 5898240L;
    v = *(const float4*)(p.Wo[d >> 16] + (d & 65535)); dst = p.dWo + d;
  }
  h4v o = {(h16)v.x, (h16)v.y, (h16)v.z, (h16)v.w};
  *(h4v*)dst = o;
}

// ---------------------------------------------------------------------------
// fp16 MFMA GEMM. BN=128, BK=64, 256 threads.
// BM=128: 4 waves 2x2, wave tile 64x64 (4x4 frags). BM=64: waves 1x4, wave
// tile 64x32 (4x2 frags). Pad 78 halves (row stride 39 dwords, odd -> spread).
// TA/TB: 0 = [row][k] (vector copy), 1/transposed-in-global = [k][row]
// (scalar transpose staging, ~4-way conflicts, acceptable).
// AF32: A is fp32 [m][k] (converted during staging).
// Outputs: chunk = n >> OSHIFT selects O[z][chunk] (col = n & mask), fp16 or
// fp32 per OUT16. RM: KV_S remap store. STATS: per-batch sum/sumsq atomics.
// ---------------------------------------------------------------------------
struct GemmP {
  const h16* A[4]; const h16* B[4]; void* O[4][3]; const float* A32[4];
};

template <int BM, int TA, int TB, int AF32, int OUT16, int RM, int STATS, int OSHIFT>
__global__ __launch_bounds__(256) void mg(GemmP p, int K, int lda, int ldb,
                                          int ldc, float* stats)
{
  constexpr int PAD = 78;
  __shared__ h16 As[BM][PAD];
  __shared__ h16 Bs[128][PAD];
  const int z = blockIdx.z;
  const h16* A = p.A[z]; const h16* B = p.B[z]; const float* A32 = p.A32[z];
  const int n0 = blockIdx.x * 128, m0 = blockIdx.y * BM;
  const int t = threadIdx.x, w = t >> 6, lg = (t >> 4) & 3, lr = t & 15;
  constexpr int MF = 4, NF = (BM == 128 ? 4 : 2);
  const int wm = (BM == 128) ? (w & 1) * 64 : 0;
  const int wn = (BM == 128) ? (w >> 1) * 64 : w * 32;

  f4v acc[MF][NF];
  #pragma unroll
  for (int i = 0; i < MF; ++i)
    #pragma unroll
    for (int j = 0; j < NF; ++j) acc[i][j] = (f4v){0.f, 0.f, 0.f, 0.f};

  for (int kt = 0; kt < K; kt += 64) {
    if (AF32) {
      #pragma unroll
      for (int it = 0; it < BM / 16; ++it) {
        const int f = t + it * 256, row = f >> 4, c4 = f & 15;
        const float4 v = *(const float4*)(A32 + (long)(m0 + row) * lda + kt + c4 * 4);
        h4v o = {(h16)v.x, (h16)v.y, (h16)v.z, (h16)v.w};
        *(h4v*)&As[row][c4 * 4] = o;
      }
    } else if (TA == 0) {
      #pragma unroll
      for (int it = 0; it < BM / 32; ++it) {
        const int f = t + it * 256, row = f >> 3, c8 = f & 7;
        *(h8v*)&As[row][c8 * 8] = *(const h8v*)(A + (long)(m0 + row) * lda + kt + c8 * 8);
      }
    } else {
      #pragma unroll
      for (int it = 0; it < BM / 32; ++it) {
        const int f = t + it * 256;
        const int kr = (BM == 128) ? (f >> 4) : (f >> 3);
        const int mc = (BM == 128) ? (f & 15) : (f & 7);
        const h8v v = *(const h8v*)(A + (long)(kt + kr) * lda + m0 + mc * 8);
        #pragma unroll
        for (int e = 0; e < 8; ++e) As[mc * 8 + e][kr] = v[e];
      }
    }
    if (TB == 0) {
      #pragma unroll
      for (int it = 0; it < 4; ++it) {
        const int f = t + it * 256, kr = f >> 4, nc = f & 15;
        const h8v v = *(const h8v*)(B + (long)(kt + kr) * ldb + n0 + nc * 8);
        #pragma unroll
        for (int e = 0; e < 8; ++e) Bs[nc * 8 + e][kr] = v[e];
      }
    } else {
      #pragma unroll
      for (int it = 0; it < 4; ++it) {
        const int f = t + it * 256, row = f >> 3, c8 = f & 7;
        *(h8v*)&Bs[row][c8 * 8] = *(const h8v*)(B + (long)(n0 + row) * ldb + kt + c8 * 8);
      }
    }
    __syncthreads();

    #pragma unroll
    for (int ks = 0; ks < 2; ++ks) {
      h8v af[MF], bf[NF];
      #pragma unroll
      for (int mf = 0; mf < MF; ++mf)
        af[mf] = *(const h8v*)&As[wm + mf * 16 + lr][ks * 32 + lg * 8];
      #pragma unroll
      for (int nf = 0; nf < NF; ++nf)
        bf[nf] = *(const h8v*)&Bs[wn + nf * 16 + lr][ks * 32 + lg * 8];
      #pragma unroll
      for (int mf = 0; mf < MF; ++mf)
        #pragma unroll
        for (int nf = 0; nf < NF; ++nf)
          acc[mf][nf] = __builtin_amdgcn_mfma_f32_16x16x32_f16(af[mf], bf[nf], acc[mf][nf], 0, 0, 0);
    }
    __syncthreads();
  }

  float s1 = 0.f, s2 = 0.f;
  #pragma unroll
  for (int mf = 0; mf < MF; ++mf)
    #pragma unroll
    for (int nf = 0; nf < NF; ++nf)
      #pragma unroll
      for (int r = 0; r < 4; ++r) {
        const int m = m0 + wm + mf * 16 + lg * 4 + r;
        const int n = n0 + wn + nf * 16 + lr;
        const float v = acc[mf][nf][r];
        if (STATS) { s1 += v; s2 += v * v; }
        if (RM) {
          ((h16*)p.O[z][0])[((long)(n >> 8) * Nn + m) * Ee + (n & 255)] = (h16)v;
        } else {
          const int chunk = n >> OSHIFT;
          const int col = n & ((1 << OSHIFT) - 1);
          if (OUT16) ((h16*)p.O[z][chunk])[(long)m * ldc + col] = (h16)v;
          else       ((float*)p.O[z][chunk])[(long)m * ldc + col] = v;
        }
      }
  if (STATS) {
    #pragma unroll
    for (int o = 1; o < 64; o <<= 1) { s1 += __shfl_xor(s1, o); s2 += __shfl_xor(s2, o); }
    if ((t & 63) == 0) { atomicAdd(&stats[z * 2], s1); atomicAdd(&stats[z * 2 + 1], s2); }
  }
}

// ---------------------------------------------------------------------------
// sim_c = softmax(attn_c * gamma1*rsqrt(var+eps), axis=-1) -> fp16 out.
// ---------------------------------------------------------------------------
__global__ __launch_bounds__(256) void softmax_c(
    const float* __restrict__ AC, const float* __restrict__ sums,
    const float* __restrict__ g1, h16* __restrict__ sim)
{
  __shared__ float red[256];
  const long r = blockIdx.x;
  const int b = (int)(r >> 10);
  const float* p = AC + r * Cc;
  const float invn = 1.f / (float)CCl;
  const float mean = sums[b * 2] * invn;
  const float var  = sums[b * 2 + 1] * invn - mean * mean;
  const float scb  = g1[0] * rsqrtf(var + EPSV);
  const int t = threadIdx.x;
  float4 v = ((const float4*)p)[t];
  v.x *= scb; v.y *= scb; v.z *= scb; v.w *= scb;
  float mx = fmaxf(fmaxf(v.x, v.y), fmaxf(v.z, v.w));
  red[t] = mx; __syncthreads();
  for (int s = 128; s > 0; s >>= 1) { if (t < s) red[t] = fmaxf(red[t], red[t + s]); __syncthreads(); }
  mx = red[0]; __syncthreads();
  v.x = __expf(v.x - mx); v.y = __expf(v.y - mx);
  v.z = __expf(v.z - mx); v.w = __expf(v.w - mx);
  red[t] = v.x + v.y + v.z + v.w; __syncthreads();
  for (int s = 128; s > 0; s >>= 1) { if (t < s) red[t] += red[t + s]; __syncthreads(); }
  const float inv = 1.f / red[0];
  h4v o = {(h16)(v.x * inv), (h16)(v.y * inv), (h16)(v.z * inv), (h16)(v.w * inv)};
  *(h4v*)&sim[r * Cc + t * 4] = o;
}

// ---------------------------------------------------------------------------
// 32x32 Gram + column sums (fp16 input, fp32 math) for analytic stage-2
// inorm scale. Blocks 0..31: K-side (12 tiles); 32..159: Q-side (3 tiles).
// ---------------------------------------------------------------------------
__global__ __launch_bounds__(256) void gram_all(
    const h16* __restrict__ Kb, const h16* __restrict__ Qb,
    float* __restrict__ Gk, float* __restrict__ km,
    float* __restrict__ Gq, float* __restrict__ qm)
{
  const int blk = blockIdx.x;
  const h16* slab; int ntiles; float* gout; float* msum;
  if (blk < 32) {
    slab = Kb + ((long)(blk >> 3) * Mm) * Ee + (blk & 7) * 32;
    ntiles = 12; gout = Gk + (long)blk * 1024; msum = km + blk * 32;
  } else {
    const int i = blk - 32, qq = i >> 5, b = (i >> 3) & 3, hd = i & 7;
    slab = Qb + (long)qq * BNE + ((long)b * Nn) * Ee + hd * 32;
    ntiles = 3; gout = Gq + (long)i * 1024; msum = qm + i * 32;
  }
  __shared__ float Ks[192][36];
  const int t = threadIdx.x;
  const int d = t >> 3, e0 = (t & 7) * 4;
  float g0 = 0.f, g1 = 0.f, g2 = 0.f, g3 = 0.f, cm = 0.f;
  for (int tile = 0; tile < ntiles; ++tile) {
    __syncthreads();
    #pragma unroll
    for (int it = 0; it < 3; ++it) {
      const int f = t + it * 256, row = f >> 2, c8 = f & 3;
      const h8v v = *(const h8v*)(slab + (long)(tile * 192 + row) * Ee + c8 * 8);
      #pragma unroll
      for (int e = 0; e < 8; ++e) Ks[row][c8 * 8 + e] = (float)v[e];
    }
    __syncthreads();
    #pragma unroll 4
    for (int m = 0; m < 192; ++m) {
      const float qd = Ks[m][d];
      const float4 qe = *(const float4*)&Ks[m][e0];
      g0 = fmaf(qd, qe.x, g0); g1 = fmaf(qd, qe.y, g1);
      g2 = fmaf(qd, qe.z, g2); g3 = fmaf(qd, qe.w, g3);
    }
    if (t < 32) {
      #pragma unroll 4
      for (int m = 0; m < 192; ++m) cm += Ks[m][t];
    }
  }
  float* gp = gout + d * 32 + e0;
  gp[0] = g0; gp[1] = g1; gp[2] = g2; gp[3] = g3;
  if (t < 32) msum[t] = cm;
}

__global__ __launch_bounds__(128) void finalize_scale2(
    const float* __restrict__ Gq, const float* __restrict__ Gk,
    const float* __restrict__ qm, const float* __restrict__ km,
    const float* __restrict__ g2, float* __restrict__ sc2)
{
  const int i = threadIdx.x;
  const int kb = i & 31;
  const float* a  = Gq + (long)i * 1024;
  const float* bb = Gk + (long)kb * 1024;
  float s = 0.f;
  for (int j = 0; j < 1024; ++j) s += a[j] * bb[j];
  float mu = 0.f;
  const float* qa = qm + i * 32;
  const float* ka = km + kb * 32;
  for (int j = 0; j < 32; ++j) mu += qa[j] * ka[j];
  const float inv = 1.f / ((float)Nn * (float)Mm);
  const float ex2 = s * inv;
  const float m1  = mu * inv;
  sc2[i] = g2[i & 7] * rsqrtf(ex2 - m1 * m1 + EPSV) * LOG2E;   // exp2 domain
}

// ---------------------------------------------------------------------------
// Swapped-QK^T MFMA flash attention. 1D grid 1152, XCD-swizzled so the 36
// blocks sharing a (b,h)'s K/V land on one XCD. 4 waves x 16 q-rows.
// Q/K fragments load direct from global fp16 (no LDS). V double-buffered
// transposed in LDS; P wave-local in LDS; 1 barrier per KV tile.
// s = mfma(K,Q): lane holds P[q=lr][kv=nf*16+lg*4+r] -> in-lane softmax.
// ---------------------------------------------------------------------------
__global__ __launch_bounds__(256) void flash3(
    const h16* __restrict__ Qb, const h16* __restrict__ Kb,
    const h16* __restrict__ Vb, const float* __restrict__ sc2,
    h16* __restrict__ ctx)
{
  constexpr int PS = 136;
  __shared__ h16 Ps[64][PS];
  __shared__ h16 Vt[2][32][PS];
  const int pidx = blockIdx.x;
  const int x = pidx & 7, rest = pidx >> 3;
  const int j = rest % 36, g = rest / 36;
  const int bh = g * 8 + x, b = bh >> 3, hd = bh & 7;
  const int nt = j % 9, q = j / 9;
  const int t = threadIdx.x, w = t >> 6, lg = (t >> 4) & 3, lr = t & 15;
  const float sc = sc2[(q << 5) + bh];

  const h16* Qp = Qb + (long)q * BNE + (long)(b * Nn + nt * 64) * Ee + hd * 32;
  const h16* Kp = Kb + ((long)b * Mm) * Ee + hd * 32;
  const h16* Vp = Vb + ((long)b * Mm) * Ee + hd * 32;

  const h8v qf = *(const h8v*)(Qp + (long)(w * 16 + lr) * Ee + lg * 8);

  #pragma unroll
  for (int it = 0; it < 2; ++it) {          // stage V tile 0
    const int f = t + it * 256, row = f >> 2, c8 = f & 3;
    const h8v v = *(const h8v*)(Vp + (long)row * Ee + c8 * 8);
    #pragma unroll
    for (int e = 0; e < 8; ++e) Vt[0][c8 * 8 + e][row] = v[e];
  }
  float m_run = -3e38f, l_run = 0.f;
  f4v cacc[2];
  cacc[0] = (f4v){0.f, 0.f, 0.f, 0.f};
  cacc[1] = (f4v){0.f, 0.f, 0.f, 0.f};
  __syncthreads();

  for (int mt = 0; mt < 18; ++mt) {
    f4v s[8];
    #pragma unroll
    for (int nf = 0; nf < 8; ++nf) {
      const h8v kf = *(const h8v*)(Kp + (long)(mt * 128 + nf * 16 + lr) * Ee + lg * 8);
      s[nf] = __builtin_amdgcn_mfma_f32_16x16x32_f16(kf, qf, (f4v){0.f, 0.f, 0.f, 0.f}, 0, 0, 0);
    }
    // prefetch next V tile into registers (write after PV, before barrier)
    h8v v0, v1;
    const int r0 = t >> 2, c0 = t & 3, r1 = (t + 256) >> 2, c1 = t & 3;
    if (mt < 17) {
      v0 = *(const h8v*)(Vp + (long)((mt + 1) * 128 + r0) * Ee + c0 * 8);
      v1 = *(const h8v*)(Vp + (long)((mt + 1) * 128 + r1) * Ee + c1 * 8);
    }
    // in-lane online softmax over this lane's 32 logits of row q=lr
    float mx = -3e38f;
    #pragma unroll
    for (int nf = 0; nf < 8; ++nf)
      #pragma unroll
      for (int r = 0; r < 4; ++r) {
        const float v = s[nf][r] * sc; s[nf][r] = v; mx = fmaxf(mx, v);
      }
    mx = fmaxf(mx, __shfl_xor(mx, 16));
    mx = fmaxf(mx, __shfl_xor(mx, 32));
    const float mnew = fmaxf(m_run, mx);
    const float corr = __builtin_amdgcn_exp2f(m_run - mnew);
    float rs = 0.f;
    #pragma unroll
    for (int nf = 0; nf < 8; ++nf)
      #pragma unroll
      for (int r = 0; r < 4; ++r) {
        const float pv = __builtin_amdgcn_exp2f(s[nf][r] - mnew);
        s[nf][r] = pv; rs += pv;
      }
    rs += __shfl_xor(rs, 16);
    rs += __shfl_xor(rs, 32);
    l_run = l_run * corr + rs;
    m_run = mnew;
    #pragma unroll
    for (int r = 0; r < 4; ++r) {
      const float cr = __shfl(corr, lg * 4 + r);
      cacc[0][r] *= cr; cacc[1][r] *= cr;
    }
    // P -> LDS (wave-local rows, no barrier needed)
    #pragma unroll
    for (int nf = 0; nf < 8; ++nf) {
      h4v pk = {(h16)s[nf][0], (h16)s[nf][1], (h16)s[nf][2], (h16)s[nf][3]};
      *(h4v*)&Ps[w * 16 + lr][nf * 16 + lg * 4] = pk;
    }
    // ctx += P V
    #pragma unroll
    for (int ks = 0; ks < 4; ++ks) {
      const h8v pf = *(const h8v*)&Ps[w * 16 + lr][ks * 32 + lg * 8];
      #pragma unroll
      for (int df = 0; df < 2; ++df) {
        const h8v vf = *(const h8v*)&Vt[mt & 1][df * 16 + lr][ks * 32 + lg * 8];
        cacc[df] = __builtin_amdgcn_mfma_f32_16x16x32_f16(pf, vf, cacc[df], 0, 0, 0);
      }
    }
    if (mt < 17) {
      const int nb = (mt + 1) & 1;
      #pragma unroll
      for (int e = 0; e < 8; ++e) Vt[nb][c0 * 8 + e][r0] = v0[e];
      #pragma unroll
      for (int e = 0; e < 8; ++e) Vt[nb][c1 * 8 + e][r1] = v1[e];
    }
    __syncthreads();
  }

  float linv[4];
  #pragma unroll
  for (int r = 0; r < 4; ++r) linv[r] = 1.f / __shfl(l_run, lg * 4 + r);
  h16* Op = ctx + (long)q * BNE + (long)(b * Nn + nt * 64) * Ee + hd * 32;
  #pragma unroll
  for (int r = 0; r < 4; ++r) {
    const long row = w * 16 + lg * 4 + r;
    Op[row * Ee + 0  + lr] = (h16)(cacc[0][r] * linv[r]);
    Op[row * Ee + 16 + lr] = (h16)(cacc[1][r] * linv[r]);
  }
}

// ---------------------------------------------------------------------------
// Launcher. Workspace (halves), ~44 MB with aliasing:
//  [0]        embC16  (2359296)  -> KVS16
//  [2359296]  QC16    (2359296)  ┐ -> sim16 (4194304)
//  [4718592]  KC16    (2359296)  ┘
//  [7077888]  VC16    (2359296)  -> ctx16
//  [9437184]  attn_c fp32 (4194304 f = 8388608 h) -> Kbuf/Vbuf/Qbuf 16
//  [17825792] Wc16 3145728 | Wkv16 131072 | Wq16 262144 | Wo16 262144
//  [21626880] stats fp32 (sums 8, Gk 32768, km 1024, Gq 131072, qm 4096, sc2 128)
// ---------------------------------------------------------------------------
extern "C" void kernel_launch(void* const* d_in, const int* in_sizes, int n_in,
                              void* d_out, int out_size, void* d_ws, size_t ws_size,
                              hipStream_t stream)
{
  (void)in_sizes; (void)n_in; (void)out_size; (void)ws_size;
  const float* emb[4] = {(const float*)d_in[0], (const float*)d_in[1],
                         (const float*)d_in[2], (const float*)d_in[3]};
  const float* embC = (const float*)d_in[4];
  const float* gamma1 = (const float*)d_in[18];
  const float* gamma2 = (const float*)d_in[20];
  float* out = (float*)d_out;

  h16* hws = (h16*)d_ws;
  h16* embC16 = hws;
  h16* QC16   = hws + 2359296L;
  h16* KC16   = hws + 4718592L;
  h16* VC16   = hws + 7077888L;
  h16* attnR  = hws + 9437184L;
  float* attnC = (float*)attnR;
  h16* Wc16  = hws + 17825792L;
  h16* Wkv16 = Wc16 + 3145728L;
  h16* Wq16  = Wkv16 + 131072L;
  h16* Wo16  = Wq16 + 262144L;
  float* stats = (float*)(hws + 21626880L);
  float* sums = stats;
  float* Gk   = stats + 8;
  float* km   = Gk + 32768;
  float* Gq   = km + 1024;
  float* qm   = Gq + 131072;
  float* sc2v = qm + 4096;
  // aliases (lifetimes verified against launch order)
  h16* sim16  = QC16;
  h16* KVS16  = embC16;
  h16* Kbuf16 = attnR;
  h16* Vbuf16 = attnR + 2359296L;
  h16* Qbuf16 = attnR + 4718592L;
  h16* ctx16  = VC16;

  hipMemsetAsync(sums, 0, 8 * sizeof(float), stream);

  {
    CvtP cp;
    cp.embC = embC;
    cp.WqC = (const float*)d_in[5]; cp.WkC = (const float*)d_in[6]; cp.WvC = (const float*)d_in[7];
    cp.Wk = (const float*)d_in[12]; cp.Wv = (const float*)d_in[13];
    for (int i = 0; i < 4; ++i) { cp.Wq[i] = (const float*)d_in[8 + i]; cp.Wo[i] = (const float*)d_in[14 + i]; }
    cp.dEmbC = embC16; cp.dWc = Wc16; cp.dWkv = Wkv16; cp.dWq = Wq16; cp.dWo = Wo16;
    convert_all<<<6016, 256, 0, stream>>>(cp);
  }

  // Stage A: [QC|KC|VC]16 = embC16 @ Wc16   (2304 x 3072 x 1024)
  {
    GemmP gp{};
    gp.A[0] = embC16; gp.B[0] = Wc16;
    gp.O[0][0] = QC16; gp.O[0][1] = KC16; gp.O[0][2] = VC16;
    mg<128,0,0,0,1,0,0,10><<<dim3(24,18,1), 256, 0, stream>>>(gp, 1024, 1024, 3072, 1024, nullptr);
  }
  // attn_c[b] = QC^T @ KC (1024x1024x576) fp32 + fused stats
  {
    GemmP gp{};
    for (int z = 0; z < 4; ++z) {
      gp.A[z] = QC16 + (long)z * 589824; gp.B[z] = KC16 + (long)z * 589824;
      gp.O[z][0] = attnC + (long)z * CCl;
    }
    mg<128,1,0,0,0,0,1,30><<<dim3(8,8,4), 256, 0, stream>>>(gp, 576, 1024, 1024, 1024, sums);
  }
  softmax_c<<<4096, 256, 0, stream>>>(attnC, sums, gamma1, sim16);
  // T_hat[b] = VC @ sim^T -> KV_S layout fp16 (576x1024x1024)
  {
    GemmP gp{};
    for (int z = 0; z < 4; ++z) {
      gp.A[z] = VC16 + (long)z * 589824; gp.B[z] = sim16 + (long)z * CCl;
      gp.O[z][0] = KVS16 + (long)z * 589824;
    }
    mg<64,0,1,0,1,1,0,30><<<dim3(8,9,4), 256, 0, stream>>>(gp, 1024, 1024, 1024, 256, nullptr);
  }
  // K/V projections: (9216 x 512 x 256)
  {
    GemmP gp{};
    gp.A[0] = KVS16; gp.B[0] = Wkv16;
    gp.O[0][0] = Kbuf16; gp.O[0][1] = Vbuf16;
    mg<128,0,0,0,1,0,0,8><<<dim3(4,72,1), 256, 0, stream>>>(gp, 256, 256, 512, 256, nullptr);
  }
  // Q projections: 4 x (2304 x 256 x 256), A fp32
  {
    GemmP gp{};
    for (int z = 0; z < 4; ++z) {
      gp.A32[z] = emb[z]; gp.B[z] = Wq16 + (long)z * 65536;
      gp.O[z][0] = Qbuf16 + (long)z * 589824;
    }
    mg<64,0,0,1,1,0,0,30><<<dim3(2,36,4), 256, 0, stream>>>(gp, 256, 256, 256, 256, nullptr);
  }
  gram_all<<<160, 256, 0, stream>>>(Kbuf16, Qbuf16, Gk, km, Gq, qm);
  finalize_scale2<<<1, 128, 0, stream>>>(Gq, Gk, qm, km, gamma2, sc2v);
  flash3<<<1152, 256, 0, stream>>>(Qbuf16, Kbuf16, Vbuf16, sc2v, ctx16);
  // output projections: 4 x (2304 x 256 x 256) -> fp32 d_out
  {
    GemmP gp{};
    for (int z = 0; z < 4; ++z) {
      gp.A[z] = ctx16 + (long)z * 589824; gp.B[z] = Wo16 + (long)z * 65536;
      gp.O[z][0] = out + (long)z * 589824;
    }
    mg<64,0,0,0,0,0,0,30><<<dim3(2,36,4), 256, 0, stream>>>(gp, 256, 256, 256, 256, nullptr);
  }
}